// Round 2
// baseline (74.185 us; speedup 1.0000x reference)
//
#include <hip/hip_runtime.h>

// TorchSTFT_75419625718337 — STFT -> (mag,phase) -> recombine -> iSTFT.
//
// Algebraic collapse (verified round 1, absmax 9.8e-4 vs 1.05e-2 threshold):
//   recomb == ft exactly (mag*cos(atan2(i,r)) = r, mag*sin(...) = i),
//   fwd_basis^T @ inv_basis = diag(win^2)/scale  (pinv of full-column-rank basis),
//   overlap-add then divides by the same window-sum it multiplied by.
// Net: out[b,0,0,t] = input_data[b,t] — the whole pipeline is the identity.
//
// Round 1 used hipMemcpyAsync (memcpy graph node): 73.6 us — the runtime
// blit/SDMA path has high per-node overhead. This round: plain copy kernel,
// float4-vectorized (16 B/lane), 4096000 floats = 1024000 float4 elements.
// Roofline: 32.8 MB HBM traffic / 6.3 TB/s ~= 5.2 us.

__global__ __launch_bounds__(256) void copy_f4(const float4* __restrict__ in,
                                               float4* __restrict__ out,
                                               int n4) {
    int i = blockIdx.x * blockDim.x + threadIdx.x;
    if (i < n4) out[i] = in[i];
}

extern "C" void kernel_launch(void* const* d_in, const int* in_sizes, int n_in,
                              void* d_out, int out_size, void* d_ws, size_t ws_size,
                              hipStream_t stream) {
    (void)in_sizes; (void)n_in; (void)d_ws; (void)ws_size;
    const float4* input_data = (const float4*)d_in[0];
    float4* out = (float4*)d_out;
    // out_size = 16*256000 = 4,096,000 floats; divisible by 4.
    int n4 = out_size / 4;
    int block = 256;
    int grid = (n4 + block - 1) / block;  // 4000 blocks
    copy_f4<<<grid, block, 0, stream>>>(input_data, out, n4);
}